// Round 2
// baseline (53461.060 us; speedup 1.0000x reference)
//
#include <hip/hip_runtime.h>
#include <hip/hip_fp16.h>

typedef float f32x4 __attribute__((ext_vector_type(4)));
typedef _Float16 half8 __attribute__((ext_vector_type(8)));
typedef _Float16 half2t __attribute__((ext_vector_type(2)));
typedef unsigned int u32;

#define DEVI static __device__ __forceinline__

constexpr int BATCH = 32;
constexpr int TLEN  = 2048;
constexpr int HDIM  = 512;
constexpr int G3    = 1536;   // 3*H

DEVI float fast_sigmoid(float x) { return 1.0f / (1.0f + __expf(-x)); }

DEVI u32 pack2h(float a, float b) {
#if __has_builtin(__builtin_amdgcn_cvt_pkrtz)
  return __builtin_bit_cast(u32, __builtin_amdgcn_cvt_pkrtz(a, b));
#else
  half2t h; h.x = (_Float16)a; h.y = (_Float16)b;
  return __builtin_bit_cast(u32, h);
#endif
}

DEVI float dot2acc(u32 w, u32 h, float acc) {
#if __has_builtin(__builtin_amdgcn_fdot2)
  return __builtin_amdgcn_fdot2(__builtin_bit_cast(half2t, w),
                                __builtin_bit_cast(half2t, h), acc, false);
#else
  half2t a = __builtin_bit_cast(half2t, w);
  half2t b = __builtin_bit_cast(half2t, h);
  return acc + (float)a.x * (float)b.x + (float)a.y * (float)b.y;
#endif
}

// ---------------- weight conversion (fp32 -> fp16) ----------------
__global__ void convert_weights(const float* __restrict__ wih, const float* __restrict__ whh,
                                _Float16* __restrict__ wih_h, _Float16* __restrict__ whh_h)
{
  const size_t n = (size_t)2 * G3 * HDIM;
  for (size_t i = (size_t)blockIdx.x * blockDim.x + threadIdx.x; i < n;
       i += (size_t)gridDim.x * blockDim.x) {
    wih_h[i] = (_Float16)wih[i];
    whh_h[i] = (_Float16)whh[i];
  }
}

// ---------------- layernorm: fp32 in -> fp16 out ----------------
__global__ __launch_bounds__(256) void ln_kernel(const float* __restrict__ x,
    const float* __restrict__ gamma, const float* __restrict__ beta,
    _Float16* __restrict__ out)
{
  const int row = blockIdx.x;
  const int tid = threadIdx.x;
  const float* xr = x + (size_t)row * HDIM;
  float a = xr[tid], b = xr[tid + 256];
  float s = a + b, ss = a * a + b * b;
#pragma unroll
  for (int m = 1; m < 64; m <<= 1) {
    s  += __shfl_xor(s, m, 64);
    ss += __shfl_xor(ss, m, 64);
  }
  __shared__ float sb[8];
  const int w = tid >> 6;
  if ((tid & 63) == 0) { sb[w] = s; sb[4 + w] = ss; }
  __syncthreads();
  s  = sb[0] + sb[1] + sb[2] + sb[3];
  ss = sb[4] + sb[5] + sb[6] + sb[7];
  const float mu   = s * (1.0f / HDIM);
  const float var  = ss * (1.0f / HDIM) - mu * mu;
  const float rstd = rsqrtf(var + 1e-5f);
  out[(size_t)row * HDIM + tid]       = (_Float16)((a - mu) * rstd * gamma[tid] + beta[tid]);
  out[(size_t)row * HDIM + tid + 256] = (_Float16)((b - mu) * rstd * gamma[tid + 256] + beta[tid + 256]);
}

// ---------------- fp16 MFMA GEMM: C[m,n] = sum_k A[m,k]*W[n,k] + bias[n] ----------------
// A rows are (b, t0+tt) of a [BATCH][TLEN][HDIM] tensor, m = b*TSEG + tt (TSEG = 1<<lgT).
__global__ __launch_bounds__(256) void gemm_f16(
    const _Float16* __restrict__ A, const _Float16* __restrict__ W,
    const float* __restrict__ bias, _Float16* __restrict__ C,
    int t0, int lgT)
{
  __shared__ _Float16 As[128][40];   // +8 halfs pad -> 80B row stride (2-way bank max)
  __shared__ _Float16 Bs[128][40];
  const int bm = blockIdx.x;
  const int bn = blockIdx.y;
  const int tid = threadIdx.x;
  const int lane = tid & 63;
  const int wv = tid >> 6;
  const int wm = wv >> 1, wn = wv & 1;
  const int l15 = lane & 15, g4 = lane >> 4;
  const int tmask = (1 << lgT) - 1;

  f32x4 zero4 = {0.f, 0.f, 0.f, 0.f};
  f32x4 acc[4][4];
#pragma unroll
  for (int i = 0; i < 4; ++i) {
#pragma unroll
    for (int j = 0; j < 4; ++j) acc[i][j] = zero4;
  }

  const int srow = tid >> 2;
  const int scol = (tid & 3) * 8;
  size_t arow[2];
#pragma unroll
  for (int r2 = 0; r2 < 2; ++r2) {
    int m = bm * 128 + r2 * 64 + srow;
    int b = m >> lgT, tt = m & tmask;
    arow[r2] = ((size_t)b * TLEN + (size_t)(t0 + tt)) * HDIM;
  }
  const size_t brow0 = (size_t)(bn * 128 + srow) * HDIM;

  for (int kt = 0; kt < HDIM; kt += 32) {
#pragma unroll
    for (int r2 = 0; r2 < 2; ++r2) {
      *(uint4*)&As[r2 * 64 + srow][scol] = *(const uint4*)&A[arow[r2] + kt + scol];
      *(uint4*)&Bs[r2 * 64 + srow][scol] = *(const uint4*)&W[brow0 + (size_t)r2 * 64 * HDIM + kt + scol];
    }
    __syncthreads();
    half8 af[4], bf[4];
#pragma unroll
    for (int i = 0; i < 4; ++i) af[i] = *(const half8*)&As[wm * 64 + i * 16 + l15][g4 * 8];
#pragma unroll
    for (int j = 0; j < 4; ++j) bf[j] = *(const half8*)&Bs[wn * 64 + j * 16 + l15][g4 * 8];
#pragma unroll
    for (int i = 0; i < 4; ++i) {
#pragma unroll
      for (int j = 0; j < 4; ++j)
        acc[i][j] = __builtin_amdgcn_mfma_f32_16x16x32_f16(af[i], bf[j], acc[i][j], 0, 0, 0);
    }
    __syncthreads();
  }
  // C/D map (verified): row = (lane>>4)*4 + reg, col = lane&15
#pragma unroll
  for (int j = 0; j < 4; ++j) {
    const int col = bn * 128 + wn * 64 + j * 16 + l15;
    const float bi = bias[col];
#pragma unroll
    for (int i = 0; i < 4; ++i) {
      const int mrow = bm * 128 + wm * 64 + i * 16 + g4 * 4;
#pragma unroll
      for (int r = 0; r < 4; ++r)
        C[(size_t)(mrow + r) * G3 + col] = (_Float16)(acc[i][j][r] + bi);
    }
  }
}

// ---------------- sync-state init ----------------
__global__ void init_sync(float* __restrict__ hbuf, u32* __restrict__ flags)
{
  const int i = blockIdx.x * 256 + threadIdx.x;
  if (i < 2 * BATCH * HDIM) hbuf[i] = 0.0f;
  if (i < BATCH * 8) flags[i] = 0u;
}

DEVI void store_out(_Float16* p, float v) { *p = (_Float16)v; }
DEVI void store_out(float* p, float v)    { *p = v; }

// ---------------- persistent GRU recurrence ----------------
// grid = 256 blocks: block = (batch g = bid>>3, chunk c = bid&7) owns output dims [c*64, c*64+64).
// 512 threads: 16 lanes per W row (each lane 32 contiguous k), 32 rows/pass, 6 passes.
// W_hh slice (192 rows x 512 fp16) lives in 96 VGPRs/thread for the whole kernel.
template <typename OUT_T>
__global__ __launch_bounds__(512, 2) void gru_rec(
    const _Float16* __restrict__ xp,   // [BATCH][TSEG][G3] (local t index)
    const u32* __restrict__ whh,       // [G3][HDIM] fp16 viewed as u32 pairs
    const float* __restrict__ bhh,     // [G3]
    OUT_T* __restrict__ hout,          // [BATCH][TLEN][HDIM]
    float* __restrict__ hbuf,          // [2][BATCH][HDIM]
    u32* __restrict__ flags,           // [BATCH][8]
    int t0, int t1, int lgT)
{
  const int g = blockIdx.x >> 3;
  const int c = blockIdx.x & 7;
  const int tid = threadIdx.x;
  const int q = tid >> 4;      // 0..31
  const int l16 = tid & 15;

  u32 wp[6][16];
  float bh[6];
#pragma unroll
  for (int p = 0; p < 6; ++p) {
    const int row = (p >> 1) * 512 + c * 64 + ((p & 1) << 5) + q;  // gate-major rows r,z,n
    const uint4* src = (const uint4*)(whh + (size_t)row * 256 + l16 * 16);
#pragma unroll
    for (int v = 0; v < 4; ++v) {
      uint4 u = src[v];
      wp[p][v * 4 + 0] = u.x; wp[p][v * 4 + 1] = u.y;
      wp[p][v * 4 + 2] = u.z; wp[p][v * 4 + 3] = u.w;
    }
    bh[p] = bhh[row];
  }

  __shared__ __align__(16) float h_l[576];   // idx -> idx + (idx>>5)*4  (bank-conflict pad)
  u32* const myflags = flags + (g << 3);

  for (int t = t0; t < t1; ++t) {
    // prefetch xp for this step before waiting on peers (independent of flags)
    float xv[6];
    {
      const size_t xrow = ((size_t)(g << lgT) + (size_t)(t - t0)) * G3;
#pragma unroll
      for (int p = 0; p < 6; ++p) {
        const int col = (p >> 1) * 512 + c * 64 + ((p & 1) << 5) + q;
        xv[p] = (float)xp[xrow + col];
      }
    }
    // wait until all 8 chunks of h version t are published
    if (tid < 8) {
      while (__hip_atomic_load(&myflags[tid], __ATOMIC_ACQUIRE, __HIP_MEMORY_SCOPE_AGENT) < (u32)t)
        __builtin_amdgcn_s_sleep(1);
    }
    __syncthreads();
    h_l[tid + ((tid >> 5) << 2)] =
        __hip_atomic_load(&hbuf[((t & 1) * BATCH + g) * HDIM + tid],
                          __ATOMIC_RELAXED, __HIP_MEMORY_SCOPE_AGENT);
    __syncthreads();

    // pack this lane's 32 h values to fp16 pairs
    u32 hp[16];
#pragma unroll
    for (int j2 = 0; j2 < 8; ++j2) {
      const float4 f = *(const float4*)&h_l[l16 * 36 + j2 * 4];
      hp[j2 * 2 + 0] = pack2h(f.x, f.y);
      hp[j2 * 2 + 1] = pack2h(f.z, f.w);
    }

    float acc[6];
#pragma unroll
    for (int p = 0; p < 6; ++p) {
      float s = 0.0f;
#pragma unroll
      for (int j = 0; j < 16; ++j) s = dot2acc(wp[p][j], hp[j], s);
      acc[p] = s;
    }
#pragma unroll
    for (int m = 1; m < 16; m <<= 1) {
#pragma unroll
      for (int p = 0; p < 6; ++p) acc[p] += __shfl_xor(acc[p], m, 64);
    }

    // gates (all 16 lanes compute identical values; stores predicated on l16==0)
    float hnew[2];
#pragma unroll
    for (int i = 0; i < 2; ++i) {
      const int sidx = c * 64 + (i << 5) + q;
      const float hprev = h_l[sidx + ((sidx >> 5) << 2)];
      const float r = fast_sigmoid(xv[i]     + acc[i]     + bh[i]);
      const float z = fast_sigmoid(xv[2 + i] + acc[2 + i] + bh[2 + i]);
      const float n = tanhf(xv[4 + i] + r * (acc[4 + i] + bh[4 + i]));
      hnew[i] = (1.0f - z) * n + z * hprev;
    }
    if (l16 == 0) {
#pragma unroll
      for (int i = 0; i < 2; ++i) {
        const int dg = c * 64 + (i << 5) + q;
        __hip_atomic_store(&hbuf[(((t + 1) & 1) * BATCH + g) * HDIM + dg], hnew[i],
                           __ATOMIC_RELAXED, __HIP_MEMORY_SCOPE_AGENT);
        store_out(&hout[((size_t)g * TLEN + t) * HDIM + dg], hnew[i]);
      }
    }
    __syncthreads();
    if (tid == 0) {
      __threadfence();
      __hip_atomic_store(&myflags[c], (u32)(t + 1), __ATOMIC_RELEASE, __HIP_MEMORY_SCOPE_AGENT);
    }
  }
}

// ---------------- host launcher ----------------
extern "C" void kernel_launch(void* const* d_in, const int* in_sizes, int n_in,
                              void* d_out, int out_size, void* d_ws, size_t ws_size,
                              hipStream_t stream)
{
  const float* x     = (const float*)d_in[0];
  const float* gamma = (const float*)d_in[1];
  const float* beta  = (const float*)d_in[2];
  const float* Wih   = (const float*)d_in[3];
  const float* Whh   = (const float*)d_in[4];
  const float* bih   = (const float*)d_in[5];
  const float* bhh   = (const float*)d_in[6];
  float* out = (float*)d_out;

  // ws layout: [xp: 32*TSEG*1536*2][h1: 67108864][wih_h][whh_h][hbuf][flags]
  const size_t wbytes  = (size_t)2 * G3 * HDIM * 2;                     // 3,145,728 each
  const size_t h1bytes = (size_t)BATCH * TLEN * HDIM * 2;               // 67,108,864
  const size_t fixed   = h1bytes + 2 * wbytes + (size_t)2 * BATCH * HDIM * 4 + 4096;
  int lgT = 11;                                                          // TSEG = 2048 if ws allows
  while (lgT > 2 && ((size_t)BATCH * ((size_t)1 << lgT) * G3 * 2 + fixed) > ws_size) --lgT;
  const int TSEG = 1 << lgT;
  const int nseg = TLEN / TSEG;

  char* ws = (char*)d_ws;
  _Float16* xp    = (_Float16*)ws;
  char* base      = ws + (size_t)BATCH * TSEG * G3 * 2;
  _Float16* h1    = (_Float16*)base;
  _Float16* wih_h = (_Float16*)(base + h1bytes);
  _Float16* whh_h = (_Float16*)(base + h1bytes + wbytes);
  float*    hbuf  = (float*)   (base + h1bytes + 2 * wbytes);
  u32*      flags = (u32*)     (base + h1bytes + 2 * wbytes + (size_t)2 * BATCH * HDIM * 4);
  _Float16* hseq  = (_Float16*)d_out;   // LN output staging (fp16) — consumed before fp32 writes

  convert_weights<<<512, 256, 0, stream>>>(Wih, Whh, wih_h, whh_h);
  ln_kernel<<<BATCH * TLEN, 256, 0, stream>>>(x, gamma, beta, hseq);

  const dim3 ggrid(BATCH * TSEG / 128, 12);

  // layer 1: xp from LN(x), recurrence -> h1 (fp16, ws)
  init_sync<<<128, 256, 0, stream>>>(hbuf, flags);
  for (int s = 0; s < nseg; ++s) {
    const int t0 = s * TSEG;
    gemm_f16<<<ggrid, 256, 0, stream>>>(hseq, wih_h, bih, xp, t0, lgT);
    gru_rec<_Float16><<<256, 512, 0, stream>>>(xp, (const u32*)whh_h, bhh,
                                               h1, hbuf, flags, t0, t0 + TSEG, lgT);
  }
  // layer 2: xp from h1, recurrence -> out (fp32, d_out)
  init_sync<<<128, 256, 0, stream>>>(hbuf, flags);
  for (int s = 0; s < nseg; ++s) {
    const int t0 = s * TSEG;
    gemm_f16<<<ggrid, 256, 0, stream>>>(h1, wih_h + (size_t)G3 * HDIM, bih + G3, xp, t0, lgT);
    gru_rec<float><<<256, 512, 0, stream>>>(xp, (const u32*)(whh_h + (size_t)G3 * HDIM), bhh + G3,
                                            out, hbuf, flags, t0, t0 + TSEG, lgT);
  }
}